// Round 3
// baseline (72.246 us; speedup 1.0000x reference)
//
#include <hip/hip_runtime.h>

// ============================================================================
// ev(b) = F1(b)^T * A * F2(b); A fixed (theta batch-uniform).
// k_prep4 (10 blocks x 1024): round-3 change — CIDX/CSGN packed into ONE
//   uint64 + ONE uint32 register per thread after the first barrier; all
//   ring_conj calls become pure-ALU (no LDS latency chains). Sign tracked as
//   a parity bit (exact ±1 flip -> bit-identical numerics).
// k_main10 (1024 x 256): UNCHANGED from round-2 (verified parity with the
//   69.5us baseline): fused group-pair t-loop, int4 staging, split fronts.
// ============================================================================

typedef _Float16 v8hf __attribute__((ext_vector_type(8)));
typedef float v4f __attribute__((ext_vector_type(4)));

struct cpx { float re, im; };
__device__ __forceinline__ cpx cmul(cpx a, cpx b) {
    return {a.re * b.re - a.im * b.im, a.re * b.im + a.im * b.re};
}

__device__ __forceinline__ cpx pget(int a, int i, int j) {
    static const float RE[4][4] = {{1, 0, 0, 1}, {0, 1, 1, 0},
                                   {0, 0, 0, 0}, {1, 0, 0, -1}};
    static const float IM[4][4] = {{0, 0, 0, 0}, {0, 0, 0, 0},
                                   {0, -1, 1, 0}, {0, 0, 0, 0}};
    cpx r; r.re = RE[a][i * 2 + j]; r.im = IM[a][i * 2 + j];
    return r;
}

// PTM entry (gate g = l*8+w, row a, col b) = 0.5 Re Tr(sig_b G^dag sig_a G)
__device__ float ptm_entry(const float* __restrict__ theta, int g, int a, int b) {
    const int l = g >> 3, w = g & 7;
    const float phi = theta[(l * 8 + w) * 3 + 0];
    const float th  = theta[(l * 8 + w) * 3 + 1];
    const float om  = theta[(l * 8 + w) * 3 + 2];
    const float c = cosf(0.5f * th), s = sinf(0.5f * th);
    const float ps = 0.5f * (phi + om), ms = 0.5f * (phi - om);
    cpx G[2][2];
    G[0][0] = {c * cosf(ps), -c * sinf(ps)};
    G[0][1] = {-s * cosf(ms), -s * sinf(ms)};
    G[1][0] = {s * cosf(ms), -s * sinf(ms)};
    G[1][1] = {c * cosf(ps), c * sinf(ps)};
    cpx M1[2][2], H[2][2];
#pragma unroll
    for (int i = 0; i < 2; ++i)
#pragma unroll
        for (int j = 0; j < 2; ++j) {
            cpx acc{0.f, 0.f};
#pragma unroll
            for (int k = 0; k < 2; ++k) {
                cpx t = cmul(pget(a, i, k), G[k][j]);
                acc.re += t.re; acc.im += t.im;
            }
            M1[i][j] = acc;
        }
#pragma unroll
    for (int i = 0; i < 2; ++i)
#pragma unroll
        for (int j = 0; j < 2; ++j) {
            cpx acc{0.f, 0.f};
#pragma unroll
            for (int k = 0; k < 2; ++k) {
                cpx gc{G[k][i].re, -G[k][i].im};
                cpx t = cmul(gc, M1[k][j]);
                acc.re += t.re; acc.im += t.im;
            }
            H[i][j] = acc;
        }
    float tr = 0.f;
#pragma unroll
    for (int i = 0; i < 2; ++i)
#pragma unroll
        for (int j = 0; j < 2; ++j) {
            cpx pb = pget(b, i, j);
            tr += pb.re * H[j][i].re - pb.im * H[j][i].im;
        }
    return 0.5f * tr;
}

__device__ void cnot_entry(int pr, int cand, int* CIDX, float* CSGN) {
    const int pc = pr >> 2, pt = pr & 3;
    const int a = cand >> 2, b2 = cand & 3;
    const int perm[4] = {0, 1, 3, 2};
    float ov = 0.f;
#pragma unroll
    for (int r = 0; r < 4; ++r)
#pragma unroll
        for (int c2 = 0; c2 < 4; ++c2) {
            const int rp = perm[r], cp = perm[c2];
            cpx Rv = cmul(pget(pc, rp >> 1, cp >> 1), pget(pt, rp & 1, cp & 1));
            cpx Kv = cmul(pget(a, r >> 1, c2 >> 1), pget(b2, r & 1, c2 & 1));
            ov += Kv.re * Rv.re + Kv.im * Rv.im;
        }
    ov *= 0.25f;
    if (ov > 0.5f) { CIDX[pr] = cand; CSGN[pr] = 1.f; }
    else if (ov < -0.5f) { CIDX[pr] = cand; CSGN[pr] = -1.f; }
}

// Register-table ring conjugation: ci = 16x4-bit CIDX, cs = 16x1-bit sign
// (bit set == CSGN=-1). Parity-accumulating; pure ALU, no LDS.
__device__ __forceinline__ int ring_conj_reg(int cur, int r,
                                             unsigned long long ci,
                                             unsigned cs, int& par) {
    for (int w = 7; w >= 0; --w) {
        const int tw = (w + r) & 7;
        const int pc = (cur >> (2 * w)) & 3;
        const int pt = (cur >> (2 * tw)) & 3;
        const int q = pc * 4 + pt;
        const int nq = (int)((ci >> (4 * q)) & 15ULL);
        par ^= (int)((cs >> q) & 1u);
        cur = (cur & ~((3 << (2 * w)) | (3 << (2 * tw))))
            | ((nq >> 2) << (2 * w)) | ((nq & 3) << (2 * tw));
    }
    return cur;
}

// ws: AF = 6912 ints (13824 halfs)
#define WS_FLOATS_NEEDED 6912

// ---------------------------------------------------------------------------
// k_prep4: 10 independent blocks x 1024; register-packed ring tables.
// ---------------------------------------------------------------------------
__global__ __launch_bounds__(1024) void k_prep4(const float* __restrict__ theta,
                                                float* __restrict__ ws) {
    _Float16* AF16 = (_Float16*)ws;
    const int tid = threadIdx.x;
    const int blk = blockIdx.x;

    if (blk == 9) {
        for (int h = tid; h < 27 * 64 * 8; h += 1024) {
            const int L = (h >> 3) & 63;
            const int jj = h & 7;
            const int m = L & 15;
            const int j = (L >> 4) * 8 + jj;
            const bool valid = (m < 12) && ((m & 3) < 3) && (j < 27);
            if (!valid) AF16[h] = (_Float16)0.f;
        }
        return;
    }

    __shared__ float Wa[4096];
    __shared__ float Wb[3072];
    __shared__ float TR[256];
    __shared__ float CSGN[16];
    __shared__ int   CIDX[16];
    __shared__ int   S1k, S1n;
    __shared__ float S1sgn;
    __shared__ int   S1w[8], S1l[8];

    const int P0 = blk / 3, P1 = blk % 3;
    const int let0 = (P0 == 0) ? 0 : ((P0 == 1) ? 3 : 2);
    const int let1 = (P1 == 0) ? 0 : ((P1 == 1) ? 3 : 2);

    if (tid < 256) TR[tid] = ptm_entry(theta, tid >> 4, (tid >> 2) & 3, tid & 3);
    else if (tid < 512) {
        const int r = tid - 256;
        cnot_entry(r >> 4, r & 15, CIDX, CSGN);
    }
    for (int i = tid; i < 4096; i += 1024) Wa[i] = 0.f;
    __syncthreads();

    // Pack the (theta-independent) CNOT conjugation tables into registers:
    // 16 entries x 4 bits -> uint64; 16 sign bits -> uint32. One-time 32 LDS
    // reads; every subsequent ring_conj step is pure ALU.
    unsigned long long cidx_pk = 0ULL;
    unsigned csgn_pk = 0u;
#pragma unroll
    for (int i2 = 0; i2 < 16; ++i2) {
        cidx_pk |= (unsigned long long)(CIDX[i2] & 15) << (4 * i2);
        csgn_pk |= (CSGN[i2] < 0.f ? 1u : 0u) << i2;
    }

    if (tid == 0) {
        int par = 0;
        int cur = ring_conj_reg(3 /* Z wire0 */, 2, cidx_pk, csgn_pk, par);
        int k = 0;
        for (int w = 0; w < 8; ++w) {
            const int ltr = (cur >> (2 * w)) & 3;
            if (ltr != 0) { S1w[k] = w; S1l[k] = ltr; ++k; }
        }
        int n = 1;
        for (int i = 0; i < k; ++i) n *= 3;
        S1sgn = par ? -1.f : 1.f; S1k = k; S1n = n;
    }
    __syncthreads();
    const int k1 = S1k, n1 = S1n;

    for (int t = tid; t < n1; t += 1024) {
        float c = S1sgn;
        int s = 0;
        int tt = t;
        for (int i = 0; i < k1; ++i) {
            const int bl = tt % 3 + 1;  // X=1,Y=2,Z=3
            tt /= 3;
            c *= TR[(8 + S1w[i]) * 16 + S1l[i] * 4 + bl];
            s |= bl << (2 * S1w[i]);
        }
        int par = 0;
        s = ring_conj_reg(s, 1, cidx_pk, csgn_pk, par);
        c = par ? -c : c;
        const int a0 = s & 3, a1 = (s >> 2) & 3;
        int d4 = 0;
#pragma unroll
        for (int w = 2; w < 8; ++w)
            d4 |= ((s >> (2 * w)) & 3) << (2 * (7 - w));
        const float v = c * TR[a0 * 4 + let0] * TR[16 + a1 * 4 + let1];
        atomicAdd(&Wa[d4], v);
    }
    __syncthreads();

    const int P3c[6] = {1, 3, 9, 27, 81, 243};
    const int N4c[6] = {1024, 256, 64, 16, 4, 1};
#pragma unroll
    for (int tl = 0; tl < 6; ++tl) {
        const int w = 7 - tl;
        const float* src = (tl & 1) ? Wb : Wa;
        float* dst = (tl & 1) ? Wa : Wb;
        const int p3 = P3c[tl];
        const int Nout = p3 * 3 * N4c[tl];
        for (int idx = tid; idx < Nout; idx += 1024) {
            const int q3 = idx % p3;
            const int rest = idx / p3;
            const int P = rest % 3;
            const int r = rest / 3;
            const int let = (P == 0) ? 0 : ((P == 1) ? 3 : 2);
            const float* ib = src + q3 + p3 * 4 * r;
            dst[idx] = ib[0] * TR[w * 16 + 0 + let]
                     + ib[p3] * TR[w * 16 + 4 + let]
                     + ib[2 * p3] * TR[w * 16 + 8 + let]
                     + ib[3 * p3] * TR[w * 16 + 12 + let];
        }
        __syncthreads();
    }

    const int m = 4 * P0 + P1;
    for (int idx = tid; idx < 729; idx += 1024) {
        const int T = idx / 27, j = idx % 27;
        const int h = (T * 64 + (j >> 3) * 16 + m) * 8 + (j & 7);
        AF16[h] = (_Float16)Wa[idx];
    }
}

// ---------------------------------------------------------------------------
// k_main10: UNCHANGED from round 2 (parity-verified vs baseline).
// ---------------------------------------------------------------------------
__device__ __forceinline__ void front_compute(const float4 xa, const float4 xb,
                                              int q, float* cw, float* msw,
                                              v8hf& bf) {
    const float xv[8] = {xa.x, xa.y, xa.z, xa.w, xb.x, xb.y, xb.z, xb.w};
#pragma unroll
    for (int w = 0; w < 8; ++w) {
        float sv, cv;
        __sincosf(xv[w], &sv, &cv);
        cw[w] = cv;
        msw[w] = -sv;
    }
    float F2[27];
    {
        const float m5v[3] = {1.f, cw[5], msw[5]};
        const float m6v[3] = {1.f, cw[6], msw[6]};
        const float m7v[3] = {1.f, cw[7], msw[7]};
#pragma unroll
        for (int a = 0; a < 3; ++a)
#pragma unroll
            for (int b2 = 0; b2 < 3; ++b2) {
                const float pp = m5v[a] * m6v[b2];
#pragma unroll
                for (int c2 = 0; c2 < 3; ++c2)
                    F2[(a * 3 + b2) * 3 + c2] = pp * m7v[c2];
            }
    }
#pragma unroll
    for (int jj = 0; jj < 8; ++jj) {
        const float c0 = F2[jj];
        const float c1 = F2[jj + 8];
        const float c2 = F2[jj + 16];
        const float c3 = (jj < 3) ? F2[jj + 24] : 0.f;
        const float v = (q == 0) ? c0 : ((q == 1) ? c1 : ((q == 2) ? c2 : c3));
        bf[jj] = (_Float16)v;
    }
}

__device__ __forceinline__ float finals10(const float* h, const float* cw,
                                          const float* msw, int q) {
    float e0 = fmaf(cw[3], h[1], h[0]); e0 = fmaf(msw[3], h[2], e0);
    float e1 = fmaf(cw[3], h[4], h[3]); e1 = fmaf(msw[3], h[5], e1);
    float e2 = fmaf(cw[3], h[7], h[6]); e2 = fmaf(msw[3], h[8], e2);
    float ev = fmaf(cw[2], e1, e0);
    ev = fmaf(msw[2], e2, ev);
    const float g0 = (q == 0) ? 1.f : ((q == 1) ? cw[0] : ((q == 2) ? msw[0] : 0.f));
    return ev * g0;
}

__global__ __launch_bounds__(256) void k_main10(const float* __restrict__ x,
                                                const int* __restrict__ wsAF,
                                                float* __restrict__ out,
                                                int ngroups) {
    __shared__ int4 AFl4[1728];  // 27648 B, same layout as before
    const int tid = threadIdx.x;
    {
        const int4* w4 = (const int4*)wsAF;
        for (int u = tid; u < 1728; u += 256) AFl4[u] = w4[u];
    }

    const int lane = tid & 63;
    const int q = lane >> 4, e = lane & 15;
    const int wave = blockIdx.x * 4 + (tid >> 6);
    const int g0 = wave * 2, g1 = g0 + 1;
    const bool v0 = g0 < ngroups, v1 = g1 < ngroups;
    const int b0 = (v0 ? g0 : 0) * 16 + e;
    const int b1 = (v1 ? g1 : (v0 ? g0 : 0)) * 16 + e;

    // Issue BOTH groups' x loads now (may stay in flight across the barrier);
    // compute front 0 now (hides LDS staging); front 1 after the barrier.
    const float4* xp0 = (const float4*)(x + (size_t)b0 * 8);
    const float4 xa0 = xp0[0], xb0 = xp0[1];
    const float4* xp1 = (const float4*)(x + (size_t)b1 * 8);
    const float4 xa1 = xp1[0], xb1 = xp1[1];

    float cw0[8], msw0[8];
    v8hf bf0;
    front_compute(xa0, xb0, q, cw0, msw0, bf0);

    __syncthreads();

    float cw1[8], msw1[8];
    v8hf bf1;
    front_compute(xa1, xb1, q, cw1, msw1, bf1);

    if (v0) {
        const v8hf* AFp = (const v8hf*)AFl4;
        const v4f zero = {0.f, 0.f, 0.f, 0.f};
        float h0[9], h1[9];
#pragma unroll
        for (int t = 0; t < 27; ++t) {
            const int a = t / 9, bb = (t / 3) % 3, c2 = t % 3;
            const v8hf frag = AFp[t * 64 + lane];  // ONE ds_read, TWO MFMAs
            v4f A0 = __builtin_amdgcn_mfma_f32_16x16x32_f16(frag, bf0, zero, 0, 0, 0);
            v4f A1 = __builtin_amdgcn_mfma_f32_16x16x32_f16(frag, bf1, zero, 0, 0, 0);
            float f0 = fmaf(cw0[1], A0[1], A0[0]); f0 = fmaf(msw0[1], A0[2], f0);
            float f1 = fmaf(cw1[1], A1[1], A1[0]); f1 = fmaf(msw1[1], A1[2], f1);
            const int hi = a * 3 + bb;
            if (c2 == 0) {
                h0[hi] = f0;
                h1[hi] = f1;
            } else if (c2 == 1) {
                h0[hi] = fmaf(cw0[4], f0, h0[hi]);
                h1[hi] = fmaf(cw1[4], f1, h1[hi]);
            } else {
                h0[hi] = fmaf(msw0[4], f0, h0[hi]);
                h1[hi] = fmaf(msw1[4], f1, h1[hi]);
            }
        }
        float ev0 = finals10(h0, cw0, msw0, q);
        float ev1 = finals10(h1, cw1, msw1, q);
        ev0 += __shfl_xor(ev0, 16, 64);
        ev0 += __shfl_xor(ev0, 32, 64);
        ev1 += __shfl_xor(ev1, 16, 64);
        ev1 += __shfl_xor(ev1, 32, 64);
        if (lane < 16) {
            out[b0] = (ev0 + 1.f) * 0.5f;
            if (v1) out[b1] = (ev1 + 1.f) * 0.5f;
        }
    }
}

// ============================================================================
// Fallback: round-1 direct statevector simulator (odd batch sizes / tiny ws).
// ============================================================================
struct c32 { float x, y; };

__device__ __forceinline__ c32 shfl_xor_c(c32 v, int mask) {
    c32 r;
    r.x = __shfl_xor(v.x, mask, 64);
    r.y = __shfl_xor(v.y, mask, 64);
    return r;
}
__device__ __forceinline__ c32 cmadd2(c32 ga, c32 a, c32 gp, c32 p) {
    c32 n;
    n.x = ga.x * a.x - ga.y * a.y + gp.x * p.x - gp.y * p.y;
    n.y = ga.x * a.y + ga.y * a.x + gp.x * p.y + gp.y * p.x;
    return n;
}
__device__ __forceinline__ c32 rx_mix(float c, float s, c32 a, c32 p) {
    c32 n;
    n.x = c * a.x + s * p.y;
    n.y = c * a.y - s * p.x;
    return n;
}
__device__ __forceinline__ void apply_rx(c32 st[4], int lane, int bb, float c, float s) {
    if (bb < 6) {
#pragma unroll
        for (int r = 0; r < 4; ++r) {
            c32 p = shfl_xor_c(st[r], 1 << bb);
            st[r] = rx_mix(c, s, st[r], p);
        }
    } else if (bb == 6) {
        c32 n0 = rx_mix(c, s, st[0], st[1]);
        c32 n1 = rx_mix(c, s, st[1], st[0]);
        c32 n2 = rx_mix(c, s, st[2], st[3]);
        c32 n3 = rx_mix(c, s, st[3], st[2]);
        st[0] = n0; st[1] = n1; st[2] = n2; st[3] = n3;
    } else {
        c32 n0 = rx_mix(c, s, st[0], st[2]);
        c32 n2 = rx_mix(c, s, st[2], st[0]);
        c32 n1 = rx_mix(c, s, st[1], st[3]);
        c32 n3 = rx_mix(c, s, st[3], st[1]);
        st[0] = n0; st[1] = n1; st[2] = n2; st[3] = n3;
    }
}
__device__ __forceinline__ void apply_rot(c32 st[4], int lane, int bb,
                                          c32 g00, c32 g01, c32 g10, c32 g11) {
    if (bb < 6) {
#pragma unroll
        for (int r = 0; r < 4; ++r) {
            c32 p = shfl_xor_c(st[r], 1 << bb);
            bool hi = (lane >> bb) & 1;
            c32 ga, gp;
            ga.x = hi ? g11.x : g00.x;
            ga.y = hi ? g11.y : g00.y;
            gp.x = hi ? g10.x : g01.x;
            gp.y = hi ? g10.y : g01.y;
            st[r] = cmadd2(ga, st[r], gp, p);
        }
    } else if (bb == 6) {
        c32 n0 = cmadd2(g00, st[0], g01, st[1]);
        c32 n1 = cmadd2(g10, st[0], g11, st[1]);
        c32 n2 = cmadd2(g00, st[2], g01, st[3]);
        c32 n3 = cmadd2(g10, st[2], g11, st[3]);
        st[0] = n0; st[1] = n1; st[2] = n2; st[3] = n3;
    } else {
        c32 n0 = cmadd2(g00, st[0], g01, st[2]);
        c32 n2 = cmadd2(g10, st[0], g11, st[2]);
        c32 n1 = cmadd2(g00, st[1], g01, st[3]);
        c32 n3 = cmadd2(g10, st[1], g11, st[3]);
        st[0] = n0; st[1] = n1; st[2] = n2; st[3] = n3;
    }
}
__device__ __forceinline__ void cswap(bool c, c32& a, c32& b) {
    c32 t = a;
    a.x = c ? b.x : a.x; a.y = c ? b.y : a.y;
    b.x = c ? t.x : b.x; b.y = c ? t.y : b.y;
}
__device__ __forceinline__ void apply_cnot(c32 st[4], int lane, int bc, int bt) {
    if (bt < 6) {
        if (bc < 6) {
            bool ctrl = (lane >> bc) & 1;
#pragma unroll
            for (int r = 0; r < 4; ++r) {
                c32 p = shfl_xor_c(st[r], 1 << bt);
                st[r].x = ctrl ? p.x : st[r].x;
                st[r].y = ctrl ? p.y : st[r].y;
            }
        } else {
#pragma unroll
            for (int r = 0; r < 4; ++r) {
                if ((r >> (bc - 6)) & 1) st[r] = shfl_xor_c(st[r], 1 << bt);
            }
        }
    } else {
        if (bc < 6) {
            bool ctrl = (lane >> bc) & 1;
            if (bt == 6) { cswap(ctrl, st[0], st[1]); cswap(ctrl, st[2], st[3]); }
            else         { cswap(ctrl, st[0], st[2]); cswap(ctrl, st[1], st[3]); }
        } else {
            if (bc == 7 && bt == 6) { c32 t = st[2]; st[2] = st[3]; st[3] = t; }
            else if (bc == 6 && bt == 7) { c32 t = st[1]; st[1] = st[3]; st[3] = t; }
        }
    }
}
__global__ __launch_bounds__(256) void qsim_kernel(const float* __restrict__ x,
                                                   const float* __restrict__ theta,
                                                   float* __restrict__ out,
                                                   int batch) {
    __shared__ float rot[2 * 8 * 8];
    const int t = threadIdx.x;
    if (t < 16) {
        const int l = t >> 3, w = t & 7;
        const float phi = theta[(l * 8 + w) * 3 + 0];
        const float th  = theta[(l * 8 + w) * 3 + 1];
        const float om  = theta[(l * 8 + w) * 3 + 2];
        const float c = cosf(0.5f * th), s = sinf(0.5f * th);
        const float p = 0.5f * (phi + om), m = 0.5f * (phi - om);
        float* g = &rot[t * 8];
        g[0] = c * cosf(p);  g[1] = -c * sinf(p);
        g[2] = -s * cosf(m); g[3] = -s * sinf(m);
        g[4] = s * cosf(m);  g[5] = -s * sinf(m);
        g[6] = c * cosf(p);  g[7] = c * sinf(p);
    }
    __syncthreads();
    const int lane = t & 63;
    const int b = blockIdx.x * 4 + (t >> 6);
    if (b >= batch) return;
    float c8 = 0.f, s8 = 0.f;
    if (lane < 8) {
        const float xv = 0.5f * x[b * 8 + lane];
        c8 = cosf(xv); s8 = sinf(xv);
    }
    c32 st[4];
#pragma unroll
    for (int r = 0; r < 4; ++r) { st[r].x = 0.f; st[r].y = 0.f; }
    if (lane == 0) st[0].x = 1.f;
#pragma unroll
    for (int w = 0; w < 8; ++w) {
        const float c = __shfl(c8, w, 64);
        const float s = __shfl(s8, w, 64);
        apply_rx(st, lane, 7 - w, c, s);
    }
#pragma unroll
    for (int l = 0; l < 2; ++l) {
#pragma unroll
        for (int w = 0; w < 8; ++w) {
            const float* g = &rot[(l * 8 + w) * 8];
            c32 g00{g[0], g[1]}, g01{g[2], g[3]}, g10{g[4], g[5]}, g11{g[6], g[7]};
            apply_rot(st, lane, 7 - w, g00, g01, g10, g11);
        }
        const int rr = l + 1;
#pragma unroll
        for (int w = 0; w < 8; ++w) apply_cnot(st, lane, 7 - w, 7 - ((w + rr) & 7));
    }
    float v = st[0].x * st[0].x + st[0].y * st[0].y
            + st[1].x * st[1].x + st[1].y * st[1].y
            - st[2].x * st[2].x - st[2].y * st[2].y
            - st[3].x * st[3].x - st[3].y * st[3].y;
#pragma unroll
    for (int off = 32; off > 0; off >>= 1) v += __shfl_xor(v, off, 64);
    if (lane == 0) out[b] = (v + 1.f) * 0.5f;
}

// ============================================================================
extern "C" void kernel_launch(void* const* d_in, const int* in_sizes, int n_in,
                              void* d_out, int out_size, void* d_ws, size_t ws_size,
                              hipStream_t stream) {
    const float* x     = (const float*)d_in[0];
    const float* theta = (const float*)d_in[1];
    float* out = (float*)d_out;
    const int batch = in_sizes[0] / 8;

    if (ws_size >= (size_t)WS_FLOATS_NEEDED * 4 + 256 && (batch & 15) == 0) {
        float* ws = (float*)d_ws;
        k_prep4<<<dim3(10), dim3(1024), 0, stream>>>(theta, ws);
        const int ngroups = batch / 16;                 // 8192
        const int blocks = (ngroups + 7) / 8;           // 2 groups/wave -> 1024
        k_main10<<<dim3(blocks), dim3(256), 0, stream>>>(
            x, (const int*)ws, out, ngroups);
    } else {
        qsim_kernel<<<dim3((batch + 3) / 4), dim3(256), 0, stream>>>(x, theta, out, batch);
    }
}

// Round 4
// 69.136 us; speedup vs baseline: 1.0450x; 1.0450x over previous
//
#include <hip/hip_runtime.h>

// ============================================================================
// ev(b) = F1(b)^T * A * F2(b); A fixed (theta batch-uniform).
// k_prep4 (10 blocks x 1024): register-packed CIDX/CSGN ring tables
//   (verified neutral r3; kept).
// k_main8 (1024 x 256): REVERTED to the round-0 verified-best structure
//   (69.5us): AF staged to LDS with scalar loads; fragments read from LDS at
//   each MFMA (no register hoist -> ~90 VGPR -> 4+ waves/SIMD); 2 groups/wave
//   processed SEQUENTIALLY (#pragma unroll 1) -> small live set.
//   r2/r3 established the fused-group variant costs ~2us (occupancy) and the
//   LDS-read savings it targets are worth ~0.
// ============================================================================

typedef _Float16 v8hf __attribute__((ext_vector_type(8)));
typedef float v4f __attribute__((ext_vector_type(4)));

struct cpx { float re, im; };
__device__ __forceinline__ cpx cmul(cpx a, cpx b) {
    return {a.re * b.re - a.im * b.im, a.re * b.im + a.im * b.re};
}

__device__ __forceinline__ cpx pget(int a, int i, int j) {
    static const float RE[4][4] = {{1, 0, 0, 1}, {0, 1, 1, 0},
                                   {0, 0, 0, 0}, {1, 0, 0, -1}};
    static const float IM[4][4] = {{0, 0, 0, 0}, {0, 0, 0, 0},
                                   {0, -1, 1, 0}, {0, 0, 0, 0}};
    cpx r; r.re = RE[a][i * 2 + j]; r.im = IM[a][i * 2 + j];
    return r;
}

// PTM entry (gate g = l*8+w, row a, col b) = 0.5 Re Tr(sig_b G^dag sig_a G)
__device__ float ptm_entry(const float* __restrict__ theta, int g, int a, int b) {
    const int l = g >> 3, w = g & 7;
    const float phi = theta[(l * 8 + w) * 3 + 0];
    const float th  = theta[(l * 8 + w) * 3 + 1];
    const float om  = theta[(l * 8 + w) * 3 + 2];
    const float c = cosf(0.5f * th), s = sinf(0.5f * th);
    const float ps = 0.5f * (phi + om), ms = 0.5f * (phi - om);
    cpx G[2][2];
    G[0][0] = {c * cosf(ps), -c * sinf(ps)};
    G[0][1] = {-s * cosf(ms), -s * sinf(ms)};
    G[1][0] = {s * cosf(ms), -s * sinf(ms)};
    G[1][1] = {c * cosf(ps), c * sinf(ps)};
    cpx M1[2][2], H[2][2];
#pragma unroll
    for (int i = 0; i < 2; ++i)
#pragma unroll
        for (int j = 0; j < 2; ++j) {
            cpx acc{0.f, 0.f};
#pragma unroll
            for (int k = 0; k < 2; ++k) {
                cpx t = cmul(pget(a, i, k), G[k][j]);
                acc.re += t.re; acc.im += t.im;
            }
            M1[i][j] = acc;
        }
#pragma unroll
    for (int i = 0; i < 2; ++i)
#pragma unroll
        for (int j = 0; j < 2; ++j) {
            cpx acc{0.f, 0.f};
#pragma unroll
            for (int k = 0; k < 2; ++k) {
                cpx gc{G[k][i].re, -G[k][i].im};
                cpx t = cmul(gc, M1[k][j]);
                acc.re += t.re; acc.im += t.im;
            }
            H[i][j] = acc;
        }
    float tr = 0.f;
#pragma unroll
    for (int i = 0; i < 2; ++i)
#pragma unroll
        for (int j = 0; j < 2; ++j) {
            cpx pb = pget(b, i, j);
            tr += pb.re * H[j][i].re - pb.im * H[j][i].im;
        }
    return 0.5f * tr;
}

__device__ void cnot_entry(int pr, int cand, int* CIDX, float* CSGN) {
    const int pc = pr >> 2, pt = pr & 3;
    const int a = cand >> 2, b2 = cand & 3;
    const int perm[4] = {0, 1, 3, 2};
    float ov = 0.f;
#pragma unroll
    for (int r = 0; r < 4; ++r)
#pragma unroll
        for (int c2 = 0; c2 < 4; ++c2) {
            const int rp = perm[r], cp = perm[c2];
            cpx Rv = cmul(pget(pc, rp >> 1, cp >> 1), pget(pt, rp & 1, cp & 1));
            cpx Kv = cmul(pget(a, r >> 1, c2 >> 1), pget(b2, r & 1, c2 & 1));
            ov += Kv.re * Rv.re + Kv.im * Rv.im;
        }
    ov *= 0.25f;
    if (ov > 0.5f) { CIDX[pr] = cand; CSGN[pr] = 1.f; }
    else if (ov < -0.5f) { CIDX[pr] = cand; CSGN[pr] = -1.f; }
}

// Register-table ring conjugation: ci = 16x4-bit CIDX, cs = 16x1-bit sign
// (bit set == CSGN=-1). Parity-accumulating; pure ALU, no LDS.
__device__ __forceinline__ int ring_conj_reg(int cur, int r,
                                             unsigned long long ci,
                                             unsigned cs, int& par) {
    for (int w = 7; w >= 0; --w) {
        const int tw = (w + r) & 7;
        const int pc = (cur >> (2 * w)) & 3;
        const int pt = (cur >> (2 * tw)) & 3;
        const int q = pc * 4 + pt;
        const int nq = (int)((ci >> (4 * q)) & 15ULL);
        par ^= (int)((cs >> q) & 1u);
        cur = (cur & ~((3 << (2 * w)) | (3 << (2 * tw))))
            | ((nq >> 2) << (2 * w)) | ((nq & 3) << (2 * tw));
    }
    return cur;
}

// ws: AF = 6912 ints (13824 halfs)
#define WS_FLOATS_NEEDED 6912

// ---------------------------------------------------------------------------
// k_prep4: 10 independent blocks x 1024; register-packed ring tables.
// ---------------------------------------------------------------------------
__global__ __launch_bounds__(1024) void k_prep4(const float* __restrict__ theta,
                                                float* __restrict__ ws) {
    _Float16* AF16 = (_Float16*)ws;
    const int tid = threadIdx.x;
    const int blk = blockIdx.x;

    if (blk == 9) {
        for (int h = tid; h < 27 * 64 * 8; h += 1024) {
            const int L = (h >> 3) & 63;
            const int jj = h & 7;
            const int m = L & 15;
            const int j = (L >> 4) * 8 + jj;
            const bool valid = (m < 12) && ((m & 3) < 3) && (j < 27);
            if (!valid) AF16[h] = (_Float16)0.f;
        }
        return;
    }

    __shared__ float Wa[4096];
    __shared__ float Wb[3072];
    __shared__ float TR[256];
    __shared__ float CSGN[16];
    __shared__ int   CIDX[16];
    __shared__ int   S1k, S1n;
    __shared__ float S1sgn;
    __shared__ int   S1w[8], S1l[8];

    const int P0 = blk / 3, P1 = blk % 3;
    const int let0 = (P0 == 0) ? 0 : ((P0 == 1) ? 3 : 2);
    const int let1 = (P1 == 0) ? 0 : ((P1 == 1) ? 3 : 2);

    if (tid < 256) TR[tid] = ptm_entry(theta, tid >> 4, (tid >> 2) & 3, tid & 3);
    else if (tid < 512) {
        const int r = tid - 256;
        cnot_entry(r >> 4, r & 15, CIDX, CSGN);
    }
    for (int i = tid; i < 4096; i += 1024) Wa[i] = 0.f;
    __syncthreads();

    // Pack the (theta-independent) CNOT conjugation tables into registers:
    // 16 entries x 4 bits -> uint64; 16 sign bits -> uint32.
    unsigned long long cidx_pk = 0ULL;
    unsigned csgn_pk = 0u;
#pragma unroll
    for (int i2 = 0; i2 < 16; ++i2) {
        cidx_pk |= (unsigned long long)(CIDX[i2] & 15) << (4 * i2);
        csgn_pk |= (CSGN[i2] < 0.f ? 1u : 0u) << i2;
    }

    if (tid == 0) {
        int par = 0;
        int cur = ring_conj_reg(3 /* Z wire0 */, 2, cidx_pk, csgn_pk, par);
        int k = 0;
        for (int w = 0; w < 8; ++w) {
            const int ltr = (cur >> (2 * w)) & 3;
            if (ltr != 0) { S1w[k] = w; S1l[k] = ltr; ++k; }
        }
        int n = 1;
        for (int i = 0; i < k; ++i) n *= 3;
        S1sgn = par ? -1.f : 1.f; S1k = k; S1n = n;
    }
    __syncthreads();
    const int k1 = S1k, n1 = S1n;

    for (int t = tid; t < n1; t += 1024) {
        float c = S1sgn;
        int s = 0;
        int tt = t;
        for (int i = 0; i < k1; ++i) {
            const int bl = tt % 3 + 1;  // X=1,Y=2,Z=3
            tt /= 3;
            c *= TR[(8 + S1w[i]) * 16 + S1l[i] * 4 + bl];
            s |= bl << (2 * S1w[i]);
        }
        int par = 0;
        s = ring_conj_reg(s, 1, cidx_pk, csgn_pk, par);
        c = par ? -c : c;
        const int a0 = s & 3, a1 = (s >> 2) & 3;
        int d4 = 0;
#pragma unroll
        for (int w = 2; w < 8; ++w)
            d4 |= ((s >> (2 * w)) & 3) << (2 * (7 - w));
        const float v = c * TR[a0 * 4 + let0] * TR[16 + a1 * 4 + let1];
        atomicAdd(&Wa[d4], v);
    }
    __syncthreads();

    const int P3c[6] = {1, 3, 9, 27, 81, 243};
    const int N4c[6] = {1024, 256, 64, 16, 4, 1};
#pragma unroll
    for (int tl = 0; tl < 6; ++tl) {
        const int w = 7 - tl;
        const float* src = (tl & 1) ? Wb : Wa;
        float* dst = (tl & 1) ? Wa : Wb;
        const int p3 = P3c[tl];
        const int Nout = p3 * 3 * N4c[tl];
        for (int idx = tid; idx < Nout; idx += 1024) {
            const int q3 = idx % p3;
            const int rest = idx / p3;
            const int P = rest % 3;
            const int r = rest / 3;
            const int let = (P == 0) ? 0 : ((P == 1) ? 3 : 2);
            const float* ib = src + q3 + p3 * 4 * r;
            dst[idx] = ib[0] * TR[w * 16 + 0 + let]
                     + ib[p3] * TR[w * 16 + 4 + let]
                     + ib[2 * p3] * TR[w * 16 + 8 + let]
                     + ib[3 * p3] * TR[w * 16 + 12 + let];
        }
        __syncthreads();
    }

    const int m = 4 * P0 + P1;
    for (int idx = tid; idx < 729; idx += 1024) {
        const int T = idx / 27, j = idx % 27;
        const int h = (T * 64 + (j >> 3) * 16 + m) * 8 + (j & 7);
        AF16[h] = (_Float16)Wa[idx];
    }
}

// ---------------------------------------------------------------------------
// k_main8: round-0 verified-best (69.5us): fragments from LDS (no hoist),
// 2 sequential groups/wave, high occupancy.
// ---------------------------------------------------------------------------
__global__ __launch_bounds__(256) void k_main8(const float* __restrict__ x,
                                               const int* __restrict__ wsAF,
                                               float* __restrict__ out,
                                               int ngroups) {
    __shared__ int AFl[6912];
    const int tid = threadIdx.x;
    for (int u = tid; u < 6912; u += 256) AFl[u] = wsAF[u];
    __syncthreads();

    const int lane = tid & 63;
    const int q = lane >> 4, e = lane & 15;
    const bool q0b = (q == 0), q1b = (q == 1), q2b = (q == 2);
    const v8hf* AFp = (const v8hf*)AFl;
    const int wave = blockIdx.x * 4 + (tid >> 6);

#pragma unroll 1
    for (int gi = 0; gi < 2; ++gi) {
        const int g = wave * 2 + gi;
        if (g >= ngroups) break;
        const int b = g * 16 + e;
        const float4* xp = (const float4*)(x + (size_t)b * 8);
        const float4 xa = xp[0], xb = xp[1];

        float cw[8], msw[8];
        {
            const float xv[8] = {xa.x, xa.y, xa.z, xa.w, xb.x, xb.y, xb.z, xb.w};
#pragma unroll
            for (int w = 0; w < 8; ++w) {
                float sv, cv;
                __sincosf(xv[w], &sv, &cv);
                cw[w] = cv;
                msw[w] = -sv;
            }
        }

        float F2[27];
        {
            const float m5v[3] = {1.f, cw[5], msw[5]};
            const float m6v[3] = {1.f, cw[6], msw[6]};
            const float m7v[3] = {1.f, cw[7], msw[7]};
#pragma unroll
            for (int a = 0; a < 3; ++a)
#pragma unroll
                for (int b2 = 0; b2 < 3; ++b2) {
                    const float pp = m5v[a] * m6v[b2];
#pragma unroll
                    for (int c2 = 0; c2 < 3; ++c2)
                        F2[(a * 3 + b2) * 3 + c2] = pp * m7v[c2];
                }
        }
        v8hf bf;
#pragma unroll
        for (int jj = 0; jj < 8; ++jj) {
            const float c0 = F2[jj];
            const float c1 = F2[jj + 8];
            const float c2 = F2[jj + 16];
            const float c3 = (jj < 3) ? F2[jj + 24] : 0.f;
            const float v = q0b ? c0 : (q1b ? c1 : (q2b ? c2 : c3));
            bf[jj] = (_Float16)v;
        }

        const v4f zero = {0.f, 0.f, 0.f, 0.f};
        float h[9];
#pragma unroll
        for (int t = 0; t < 27; ++t) {
            const int a = t / 9, b2 = (t / 3) % 3, c2 = t % 3;
            v4f acc = __builtin_amdgcn_mfma_f32_16x16x32_f16(
                AFp[t * 64 + lane], bf, zero, 0, 0, 0);
            float f = fmaf(cw[1], acc[1], acc[0]);
            f = fmaf(msw[1], acc[2], f);
            if (c2 == 0)      h[a * 3 + b2] = f;
            else if (c2 == 1) h[a * 3 + b2] = fmaf(cw[4], f, h[a * 3 + b2]);
            else              h[a * 3 + b2] = fmaf(msw[4], f, h[a * 3 + b2]);
        }
        float e0 = fmaf(cw[3], h[1], h[0]); e0 = fmaf(msw[3], h[2], e0);
        float e1 = fmaf(cw[3], h[4], h[3]); e1 = fmaf(msw[3], h[5], e1);
        float e2 = fmaf(cw[3], h[7], h[6]); e2 = fmaf(msw[3], h[8], e2);
        float ev = fmaf(cw[2], e1, e0);
        ev = fmaf(msw[2], e2, ev);
        const float g0 = q0b ? 1.f : (q1b ? cw[0] : (q2b ? msw[0] : 0.f));
        ev *= g0;

        ev += __shfl_xor(ev, 16, 64);
        ev += __shfl_xor(ev, 32, 64);
        if (lane < 16) out[b] = (ev + 1.f) * 0.5f;
    }
}

// ============================================================================
// Fallback: round-1 direct statevector simulator (odd batch sizes / tiny ws).
// ============================================================================
struct c32 { float x, y; };

__device__ __forceinline__ c32 shfl_xor_c(c32 v, int mask) {
    c32 r;
    r.x = __shfl_xor(v.x, mask, 64);
    r.y = __shfl_xor(v.y, mask, 64);
    return r;
}
__device__ __forceinline__ c32 cmadd2(c32 ga, c32 a, c32 gp, c32 p) {
    c32 n;
    n.x = ga.x * a.x - ga.y * a.y + gp.x * p.x - gp.y * p.y;
    n.y = ga.x * a.y + ga.y * a.x + gp.x * p.y + gp.y * p.x;
    return n;
}
__device__ __forceinline__ c32 rx_mix(float c, float s, c32 a, c32 p) {
    c32 n;
    n.x = c * a.x + s * p.y;
    n.y = c * a.y - s * p.x;
    return n;
}
__device__ __forceinline__ void apply_rx(c32 st[4], int lane, int bb, float c, float s) {
    if (bb < 6) {
#pragma unroll
        for (int r = 0; r < 4; ++r) {
            c32 p = shfl_xor_c(st[r], 1 << bb);
            st[r] = rx_mix(c, s, st[r], p);
        }
    } else if (bb == 6) {
        c32 n0 = rx_mix(c, s, st[0], st[1]);
        c32 n1 = rx_mix(c, s, st[1], st[0]);
        c32 n2 = rx_mix(c, s, st[2], st[3]);
        c32 n3 = rx_mix(c, s, st[3], st[2]);
        st[0] = n0; st[1] = n1; st[2] = n2; st[3] = n3;
    } else {
        c32 n0 = rx_mix(c, s, st[0], st[2]);
        c32 n2 = rx_mix(c, s, st[2], st[0]);
        c32 n1 = rx_mix(c, s, st[1], st[3]);
        c32 n3 = rx_mix(c, s, st[3], st[1]);
        st[0] = n0; st[1] = n1; st[2] = n2; st[3] = n3;
    }
}
__device__ __forceinline__ void apply_rot(c32 st[4], int lane, int bb,
                                          c32 g00, c32 g01, c32 g10, c32 g11) {
    if (bb < 6) {
#pragma unroll
        for (int r = 0; r < 4; ++r) {
            c32 p = shfl_xor_c(st[r], 1 << bb);
            bool hi = (lane >> bb) & 1;
            c32 ga, gp;
            ga.x = hi ? g11.x : g00.x;
            ga.y = hi ? g11.y : g00.y;
            gp.x = hi ? g10.x : g01.x;
            gp.y = hi ? g10.y : g01.y;
            st[r] = cmadd2(ga, st[r], gp, p);
        }
    } else if (bb == 6) {
        c32 n0 = cmadd2(g00, st[0], g01, st[1]);
        c32 n1 = cmadd2(g10, st[0], g11, st[1]);
        c32 n2 = cmadd2(g00, st[2], g01, st[3]);
        c32 n3 = cmadd2(g10, st[2], g11, st[3]);
        st[0] = n0; st[1] = n1; st[2] = n2; st[3] = n3;
    } else {
        c32 n0 = cmadd2(g00, st[0], g01, st[2]);
        c32 n2 = cmadd2(g10, st[0], g11, st[2]);
        c32 n1 = cmadd2(g00, st[1], g01, st[3]);
        c32 n3 = cmadd2(g10, st[1], g11, st[3]);
        st[0] = n0; st[1] = n1; st[2] = n2; st[3] = n3;
    }
}
__device__ __forceinline__ void cswap(bool c, c32& a, c32& b) {
    c32 t = a;
    a.x = c ? b.x : a.x; a.y = c ? b.y : a.y;
    b.x = c ? t.x : b.x; b.y = c ? t.y : b.y;
}
__device__ __forceinline__ void apply_cnot(c32 st[4], int lane, int bc, int bt) {
    if (bt < 6) {
        if (bc < 6) {
            bool ctrl = (lane >> bc) & 1;
#pragma unroll
            for (int r = 0; r < 4; ++r) {
                c32 p = shfl_xor_c(st[r], 1 << bt);
                st[r].x = ctrl ? p.x : st[r].x;
                st[r].y = ctrl ? p.y : st[r].y;
            }
        } else {
#pragma unroll
            for (int r = 0; r < 4; ++r) {
                if ((r >> (bc - 6)) & 1) st[r] = shfl_xor_c(st[r], 1 << bt);
            }
        }
    } else {
        if (bc < 6) {
            bool ctrl = (lane >> bc) & 1;
            if (bt == 6) { cswap(ctrl, st[0], st[1]); cswap(ctrl, st[2], st[3]); }
            else         { cswap(ctrl, st[0], st[2]); cswap(ctrl, st[1], st[3]); }
        } else {
            if (bc == 7 && bt == 6) { c32 t = st[2]; st[2] = st[3]; st[3] = t; }
            else if (bc == 6 && bt == 7) { c32 t = st[1]; st[1] = st[3]; st[3] = t; }
        }
    }
}
__global__ __launch_bounds__(256) void qsim_kernel(const float* __restrict__ x,
                                                   const float* __restrict__ theta,
                                                   float* __restrict__ out,
                                                   int batch) {
    __shared__ float rot[2 * 8 * 8];
    const int t = threadIdx.x;
    if (t < 16) {
        const int l = t >> 3, w = t & 7;
        const float phi = theta[(l * 8 + w) * 3 + 0];
        const float th  = theta[(l * 8 + w) * 3 + 1];
        const float om  = theta[(l * 8 + w) * 3 + 2];
        const float c = cosf(0.5f * th), s = sinf(0.5f * th);
        const float p = 0.5f * (phi + om), m = 0.5f * (phi - om);
        float* g = &rot[t * 8];
        g[0] = c * cosf(p);  g[1] = -c * sinf(p);
        g[2] = -s * cosf(m); g[3] = -s * sinf(m);
        g[4] = s * cosf(m);  g[5] = -s * sinf(m);
        g[6] = c * cosf(p);  g[7] = c * sinf(p);
    }
    __syncthreads();
    const int lane = t & 63;
    const int b = blockIdx.x * 4 + (t >> 6);
    if (b >= batch) return;
    float c8 = 0.f, s8 = 0.f;
    if (lane < 8) {
        const float xv = 0.5f * x[b * 8 + lane];
        c8 = cosf(xv); s8 = sinf(xv);
    }
    c32 st[4];
#pragma unroll
    for (int r = 0; r < 4; ++r) { st[r].x = 0.f; st[r].y = 0.f; }
    if (lane == 0) st[0].x = 1.f;
#pragma unroll
    for (int w = 0; w < 8; ++w) {
        const float c = __shfl(c8, w, 64);
        const float s = __shfl(s8, w, 64);
        apply_rx(st, lane, 7 - w, c, s);
    }
#pragma unroll
    for (int l = 0; l < 2; ++l) {
#pragma unroll
        for (int w = 0; w < 8; ++w) {
            const float* g = &rot[(l * 8 + w) * 8];
            c32 g00{g[0], g[1]}, g01{g[2], g[3]}, g10{g[4], g[5]}, g11{g[6], g[7]};
            apply_rot(st, lane, 7 - w, g00, g01, g10, g11);
        }
        const int rr = l + 1;
#pragma unroll
        for (int w = 0; w < 8; ++w) apply_cnot(st, lane, 7 - w, 7 - ((w + rr) & 7));
    }
    float v = st[0].x * st[0].x + st[0].y * st[0].y
            + st[1].x * st[1].x + st[1].y * st[1].y
            - st[2].x * st[2].x - st[2].y * st[2].y
            - st[3].x * st[3].x - st[3].y * st[3].y;
#pragma unroll
    for (int off = 32; off > 0; off >>= 1) v += __shfl_xor(v, off, 64);
    if (lane == 0) out[b] = (v + 1.f) * 0.5f;
}

// ============================================================================
extern "C" void kernel_launch(void* const* d_in, const int* in_sizes, int n_in,
                              void* d_out, int out_size, void* d_ws, size_t ws_size,
                              hipStream_t stream) {
    const float* x     = (const float*)d_in[0];
    const float* theta = (const float*)d_in[1];
    float* out = (float*)d_out;
    const int batch = in_sizes[0] / 8;

    if (ws_size >= (size_t)WS_FLOATS_NEEDED * 4 + 256 && (batch & 15) == 0) {
        float* ws = (float*)d_ws;
        k_prep4<<<dim3(10), dim3(1024), 0, stream>>>(theta, ws);
        const int ngroups = batch / 16;                 // 8192
        const int blocks = (ngroups + 7) / 8;           // 2 groups/wave -> 1024
        k_main8<<<dim3(blocks), dim3(256), 0, stream>>>(
            x, (const int*)ws, out, ngroups);
    } else {
        qsim_kernel<<<dim3((batch + 3) / 4), dim3(256), 0, stream>>>(x, theta, out, batch);
    }
}